// Round 12
// baseline (414.065 us; speedup 1.0000x reference)
//
#include <hip/hip_runtime.h>

#define B_ 4
#define L_ 4096
#define D_ 1152
#define T_ (B_*L_)      // 16384 tokens
#define D3_ 384
#define H_ 16

typedef __attribute__((ext_vector_type(4))) float f32x4;
typedef __attribute__((ext_vector_type(8))) __bf16 bf16x8;
typedef __attribute__((ext_vector_type(8))) unsigned short u16x8;
typedef __attribute__((ext_vector_type(4))) unsigned short u16x4;

__device__ __forceinline__ unsigned short f2bf(float f) {
  unsigned int u = __float_as_uint(f);
  u += 0x7fffu + ((u >> 16) & 1u);
  return (unsigned short)(u >> 16);
}
__device__ __forceinline__ float bf2f(unsigned short h) {
  return __uint_as_float(((unsigned int)h) << 16);
}

__device__ __forceinline__ void gl_lds16(const unsigned short* g, unsigned short* l) {
  __builtin_amdgcn_global_load_lds(
      (const __attribute__((address_space(1))) unsigned int*)g,
      (__attribute__((address_space(3))) unsigned int*)l,
      16, 0, 0);
}

// ---------------- LayerNorm ----------------
__global__ __launch_bounds__(256) void ln_kernel(const float* __restrict__ x,
                                                 const float* __restrict__ gamma,
                                                 const float* __restrict__ beta,
                                                 unsigned short* __restrict__ xn) {
  const int row = blockIdx.x;
  const int tid = threadIdx.x;
  const float4* xr = (const float4*)(x + (size_t)row * D_);
  float4 v0 = xr[tid];
  float4 v1 = {0.f, 0.f, 0.f, 0.f};
  const bool has2 = tid < 32;
  if (has2) v1 = xr[256 + tid];
  float s  = v0.x + v0.y + v0.z + v0.w + v1.x + v1.y + v1.z + v1.w;
  float s2 = v0.x*v0.x + v0.y*v0.y + v0.z*v0.z + v0.w*v0.w
           + v1.x*v1.x + v1.y*v1.y + v1.z*v1.z + v1.w*v1.w;
#pragma unroll
  for (int o = 32; o > 0; o >>= 1) { s += __shfl_down(s, o); s2 += __shfl_down(s2, o); }
  __shared__ float red[8];
  int wid = tid >> 6, lane = tid & 63;
  if (lane == 0) { red[wid] = s; red[4 + wid] = s2; }
  __syncthreads();
  float ts  = red[0] + red[1] + red[2] + red[3];
  float ts2 = red[4] + red[5] + red[6] + red[7];
  const float inv = 1.f / (float)D_;
  float mean = ts * inv;
  float var  = ts2 * inv - mean * mean;
  float rstd = rsqrtf(var + 1e-6f);
  const float4* gm = (const float4*)gamma;
  const float4* bt = (const float4*)beta;
  unsigned short* xo = xn + (size_t)row * D_;
  {
    float4 gv = gm[tid], bv = bt[tid];
    u16x4 r;
    r[0] = f2bf((v0.x - mean) * rstd * gv.x + bv.x);
    r[1] = f2bf((v0.y - mean) * rstd * gv.y + bv.y);
    r[2] = f2bf((v0.z - mean) * rstd * gv.z + bv.z);
    r[3] = f2bf((v0.w - mean) * rstd * gv.w + bv.w);
    *(u16x4*)(xo + tid * 4) = r;
  }
  if (has2) {
    float4 gv = gm[256 + tid], bv = bt[256 + tid];
    u16x4 r;
    r[0] = f2bf((v1.x - mean) * rstd * gv.x + bv.x);
    r[1] = f2bf((v1.y - mean) * rstd * gv.y + bv.y);
    r[2] = f2bf((v1.z - mean) * rstd * gv.z + bv.z);
    r[3] = f2bf((v1.w - mean) * rstd * gv.w + bv.w);
    *(u16x4*)(xo + (256 + tid) * 4) = r;
  }
}

// ---------------- Weight converts ----------------
__global__ void cvt_cat_wqkvg(const float* __restrict__ Wq, const float* __restrict__ Wk,
                              const float* __restrict__ Wv, const float* __restrict__ Wg,
                              unsigned short* __restrict__ out) {
  int i = blockIdx.x * 256 + threadIdx.x;
  if (i >= 4 * 147456) return;
  int p = i / 147456;
  int r = i - p * 147456;
  const float* W = (p == 0) ? Wq : (p == 1) ? Wk : (p == 2) ? Wv : Wg;
  out[i] = f2bf(W[r]);
}

// Wo -> bf16, padded to 1280 rows (rows >= 1152 zero)
__global__ void cvt_wo_pad(const float* __restrict__ in, unsigned short* __restrict__ out) {
  int i = blockIdx.x * 256 + threadIdx.x;
  if (i >= 1280 * 1152) return;
  int r = i / 1152;
  out[i] = (r < 1152) ? f2bf(in[i]) : (unsigned short)0;
}

// ---------------- 256x256 8-phase deep-pipelined bf16 GEMM ----------------
// BK=64, 512 thr = 8 waves (2M x 4N), wave-out 128x64, acc[8][4].
// LDS 128KB: dbuf d in {0,1} at d*65536; halves A0,A1,B0,B1 of 16KB each
// (A-half h = tile rows h*128..+127 x 64K). Byte within half:
//   rho*128 + slot*16, slot = chunk ^ (rho&7)  (zero-extra-conflict XOR).
// Stage: 1 half per phase into the region consumed >=1 barrier earlier.
// vmcnt(4) @P4 (forces B1(O) for P5), vmcnt(6) @P8 (forces tile E+2) -- never 0.

#define SBR __builtin_amdgcn_sched_barrier(0)
#define BARX do { SBR; __builtin_amdgcn_s_barrier(); SBR; } while (0)
#define LG0 do { asm volatile("s_waitcnt lgkmcnt(0)" ::: "memory"); SBR; } while (0)

#define MQ(I0, AF, BF)                                                         \
  __builtin_amdgcn_s_setprio(1);                                               \
  _Pragma("unroll") for (int i_ = 0; i_ < 4; ++i_)                             \
    _Pragma("unroll") for (int j_ = 0; j_ < 4; ++j_)                           \
      acc[(I0) + i_][j_] = __builtin_amdgcn_mfma_f32_16x16x32_bf16(            \
          AF[(I0) + i_], BF[j_], acc[(I0) + i_][j_], 0, 0, 0);                 \
  __builtin_amdgcn_s_setprio(0);

// stage one 128-row x 64K half of `tile` from G (row rowb..) into dstb (char*)
#define STG(G, rowb, tile, dstb)                                               \
  {                                                                            \
    const int r_ = wid * 16 + (lane >> 3);                                     \
    const int c_ = ((lane & 7) ^ (lane >> 3)) * 8;                             \
    const unsigned short* g_ = (G) + (size_t)((rowb) + r_) * K2 + (tile) * 64 + c_; \
    gl_lds16(g_, (unsigned short*)((dstb) + wid * 2048));                      \
    gl_lds16(g_ + (size_t)8 * K2, (unsigned short*)((dstb) + wid * 2048 + 1024)); \
  }

template<int EPI, int K2, int NKT>
__global__ __launch_bounds__(512, 2) void gemm8p(
    const unsigned short* __restrict__ A, const unsigned short* __restrict__ Bt,
    int Nout,
    unsigned short* __restrict__ Cb,
    const float* __restrict__ b0, const float* __restrict__ b1,
    const float* __restrict__ b2, const float* __restrict__ b3,
    float* __restrict__ Cf, const float* __restrict__ bo,
    const float* __restrict__ xres, const float* __restrict__ gs) {
  extern __shared__ char lds[];
  char* d0 = lds;
  char* d1 = lds + 65536;
  const int tid = threadIdx.x;
  const int nwg = gridDim.x * gridDim.y;
  const int flat = blockIdx.y * gridDim.x + blockIdx.x;
  const int swz = (flat & 7) * (nwg >> 3) + (flat >> 3);
  const int bn = swz % gridDim.x, bm = swz / gridDim.x;
  const int wid = tid >> 6, lane = tid & 63;
  const int wm = wid >> 2, wn = wid & 3;
  const int lrow = lane & 15, kq = lane >> 4;

  const unsigned short* Ab = A + (size_t)bm * 256 * K2;
  const unsigned short* Bb = Bt + (size_t)bn * 256 * K2;

  f32x4 acc[8][4];
#pragma unroll
  for (int m = 0; m < 8; ++m)
#pragma unroll
    for (int n = 0; n < 4; ++n) acc[m][n] = (f32x4){0.f, 0.f, 0.f, 0.f};

  // read byte-offsets within a dbuf
  const int kx0 = ((kq ^ (lrow & 7)) * 16);          // k-half 0 slot
  const int kx1 = (((4 | kq) ^ (lrow & 7)) * 16);    // k-half 1 slot
  int aoff[8], boffv[4];
#pragma unroll
  for (int i = 0; i < 8; ++i) aoff[i] = wm * 16384 + (i * 16 + lrow) * 128;
#pragma unroll
  for (int j = 0; j < 4; ++j)
    boffv[j] = 32768 + (wn >> 1) * 16384 + ((wn & 1) * 64 + j * 16 + lrow) * 128;

  // prologue: tile0 -> d0 (4 halves), tile1 -> d1 (A0,A1,B0); B1(1) at it0-P1
  STG(Ab, 0,   0, d0);
  STG(Ab, 128, 0, d0 + 16384);
  STG(Bb, 0,   0, d0 + 32768);
  STG(Bb, 128, 0, d0 + 49152);
  STG(Ab, 0,   1, d1);
  STG(Ab, 128, 1, d1 + 16384);
  STG(Bb, 0,   1, d1 + 32768);
  asm volatile("s_waitcnt vmcnt(6)" ::: "memory");   // tile0 landed; tile1 (3 halves) in flight
  SBR;
  __builtin_amdgcn_s_barrier();

  constexpr int NIT = NKT / 2;
#pragma unroll 1
  for (int it = 0; it < NIT; ++it) {
    const int O = 2 * it + 1, e2 = 2 * it + 2, o2 = 2 * it + 3;
    const bool gE = e2 < NKT, gO = o2 < NKT;
    bf16x8 af0[8], af1[8], bfr0[4], bfr1[4];

    // ---- P1: read E(k0); stage B1(O)->d1 ----
#pragma unroll
    for (int j = 0; j < 4; ++j) bfr0[j] = *(const bf16x8*)(d0 + boffv[j] + kx0);
#pragma unroll
    for (int i = 0; i < 8; ++i) af0[i] = *(const bf16x8*)(d0 + aoff[i] + kx0);
    STG(Bb, 128, O, d1 + 49152);
    BARX; LG0; MQ(0, af0, bfr0); BARX;
    // ---- P2: read A(E,k1) ----
#pragma unroll
    for (int i = 0; i < 8; ++i) af1[i] = *(const bf16x8*)(d0 + aoff[i] + kx1);
    BARX; LG0; MQ(4, af0, bfr0); BARX;
    // ---- P3: read B(E,k1); stage A0(e2)->d0 ----
#pragma unroll
    for (int j = 0; j < 4; ++j) bfr1[j] = *(const bf16x8*)(d0 + boffv[j] + kx1);
    if (gE) STG(Ab, 0, e2, d0);
    BARX; LG0; MQ(0, af1, bfr1); BARX;
    // ---- P4: stage A1(e2)->d0; vmcnt forces B1(O) landed ----
    if (gE) {
      STG(Ab, 128, e2, d0 + 16384);
      asm volatile("s_waitcnt vmcnt(4)" ::: "memory");
    } else {
      asm volatile("s_waitcnt vmcnt(0)" ::: "memory");
    }
    SBR;
    BARX; LG0; MQ(4, af1, bfr1); BARX;
    // ---- P5: read O(k0); stage B0(e2)->d0 ----
#pragma unroll
    for (int j = 0; j < 4; ++j) bfr0[j] = *(const bf16x8*)(d1 + boffv[j] + kx0);
#pragma unroll
    for (int i = 0; i < 8; ++i) af0[i] = *(const bf16x8*)(d1 + aoff[i] + kx0);
    if (gE) STG(Bb, 0, e2, d0 + 32768);
    BARX; LG0; MQ(0, af0, bfr0); BARX;
    // ---- P6: read A(O,k1); stage B1(e2)->d0 ----
#pragma unroll
    for (int i = 0; i < 8; ++i) af1[i] = *(const bf16x8*)(d1 + aoff[i] + kx1);
    if (gE) STG(Bb, 128, e2, d0 + 49152);
    BARX; LG0; MQ(4, af0, bfr0); BARX;
    // ---- P7: read B(O,k1); stage A0(o2)->d1 ----
#pragma unroll
    for (int j = 0; j < 4; ++j) bfr1[j] = *(const bf16x8*)(d1 + boffv[j] + kx1);
    if (gO) STG(Ab, 0, o2, d1);
    BARX; LG0; MQ(0, af1, bfr1); BARX;
    // ---- P8: stage A1(o2),B0(o2)->d1; vmcnt forces tile e2 landed ----
    if (gO) {
      STG(Ab, 128, o2, d1 + 16384);
      STG(Bb, 0, o2, d1 + 32768);
    }
    asm volatile("s_waitcnt vmcnt(6)" ::: "memory");
    SBR;
    BARX; LG0; MQ(4, af1, bfr1); BARX;
  }

  // Epilogue. D layout: col = lane&15, row = (lane>>4)*4 + reg  [m89-verified]
  const int rbase = bm * 256 + wm * 128 + kq * 4;
  const int cbase = bn * 256 + wn * 64 + lrow;
  float gv = (EPI == 1) ? gs[0] : 0.f;
#pragma unroll
  for (int m = 0; m < 8; ++m) {
#pragma unroll
    for (int n = 0; n < 4; ++n) {
      int col = cbase + n * 16;
      if (EPI == 0) {
        int p = (col < 384) ? 0 : (col < 768) ? 1 : (col < 1152) ? 2 : 3;
        const float* bp = (p == 0) ? b0 : (p == 1) ? b1 : (p == 2) ? b2 : b3;
        float bias = bp[col - p * 384];
#pragma unroll
        for (int i = 0; i < 4; ++i) {
          int row = rbase + m * 16 + i;
          Cb[(size_t)row * Nout + col] = f2bf(acc[m][n][i] + bias);
        }
      } else {
        if (col < 1152) {
          float bias = bo[col];
#pragma unroll
          for (int i = 0; i < 4; ++i) {
            int row = rbase + m * 16 + i;
            size_t idx = (size_t)row * Nout + col;
            Cf[idx] = acc[m][n][i] + bias + xres[idx] * gv;
          }
        }
      }
    }
  }
}

// ---------------- 3x3 attention + gate ----------------
__global__ __launch_bounds__(256) void attn_kernel(const unsigned short* __restrict__ QKVG,
                                                   unsigned short* __restrict__ Hout) {
  int u = blockIdx.x * 256 + threadIdx.x;
  int h = u & 15;
  int ti = u >> 4;
  int i = ti % 3;
  int t = ti / 3;
  const unsigned short* base = QKVG + (size_t)t * 3 * 1536;
  const int co = h * 24;

  float q[24];
#pragma unroll
  for (int c = 0; c < 3; ++c) {
    u16x8 w = *(const u16x8*)(base + (size_t)i * 1536 + co + c * 8);
#pragma unroll
    for (int e = 0; e < 8; ++e) q[c * 8 + e] = bf2f(w[e]);
  }
  float s[3];
#pragma unroll
  for (int j = 0; j < 3; ++j) {
    float a = 0.f;
#pragma unroll
    for (int c = 0; c < 3; ++c) {
      u16x8 w = *(const u16x8*)(base + (size_t)j * 1536 + 384 + co + c * 8);
#pragma unroll
      for (int e = 0; e < 8; ++e) a += q[c * 8 + e] * bf2f(w[e]);
    }
    s[j] = a * 0.11785113019775793f;
  }
  float mx = fmaxf(s[0], fmaxf(s[1], s[2]));
  float e0 = __expf(s[0] - mx), e1 = __expf(s[1] - mx), e2 = __expf(s[2] - mx);
  float inv = 1.f / (e0 + e1 + e2);
  float p0 = e0 * inv, p1 = e1 * inv, p2 = e2 * inv;

  float o[24];
#pragma unroll
  for (int d = 0; d < 24; ++d) o[d] = 0.f;
  float pj[3] = {p0, p1, p2};
#pragma unroll
  for (int j = 0; j < 3; ++j) {
#pragma unroll
    for (int c = 0; c < 3; ++c) {
      u16x8 w = *(const u16x8*)(base + (size_t)j * 1536 + 768 + co + c * 8);
#pragma unroll
      for (int e = 0; e < 8; ++e) o[c * 8 + e] += pj[j] * bf2f(w[e]);
    }
  }
  unsigned short* op = Hout + (size_t)t * 1152 + (size_t)i * 384 + co;
#pragma unroll
  for (int c = 0; c < 3; ++c) {
    u16x8 w = *(const u16x8*)(base + (size_t)i * 1536 + 1152 + co + c * 8);
    u16x8 r;
#pragma unroll
    for (int e = 0; e < 8; ++e) {
      float gvv = bf2f(w[e]);
      float sg = 1.f / (1.f + __expf(-gvv));
      r[e] = f2bf(o[c * 8 + e] * sg);
    }
    *(u16x8*)(op + c * 8) = r;
  }
}

extern "C" void kernel_launch(void* const* d_in, const int* in_sizes, int n_in,
                              void* d_out, int out_size, void* d_ws, size_t ws_size,
                              hipStream_t stream) {
  const float* x    = (const float*)d_in[0];
  const float* ln_g = (const float*)d_in[1];
  const float* ln_b = (const float*)d_in[2];
  const float* Wq   = (const float*)d_in[3];
  const float* bq   = (const float*)d_in[4];
  const float* Wk   = (const float*)d_in[5];
  const float* bk   = (const float*)d_in[6];
  const float* Wv   = (const float*)d_in[7];
  const float* bv   = (const float*)d_in[8];
  const float* Wg   = (const float*)d_in[9];
  const float* bg   = (const float*)d_in[10];
  const float* Wo   = (const float*)d_in[11];
  const float* bo   = (const float*)d_in[12];
  const float* g    = (const float*)d_in[13];
  float* out = (float*)d_out;

  char* ws = (char*)d_ws;
  size_t off = 0;
  unsigned short* xn    = (unsigned short*)(ws + off); off += (size_t)T_ * D_ * 2;
  unsigned short* Wqkvg = (unsigned short*)(ws + off); off += (size_t)1536 * 384 * 2;
  unsigned short* Wob   = (unsigned short*)(ws + off); off += (size_t)1280 * 1152 * 2;
  unsigned short* QKVG  = (unsigned short*)(ws + off); off += (size_t)T_ * 3 * 1536 * 2;
  unsigned short* Hf    = (unsigned short*)(ws + off); off += (size_t)T_ * D_ * 2;

  const int LDS_BYTES = 131072;
  (void)hipFuncSetAttribute(reinterpret_cast<const void*>(&gemm8p<0, 384, 6>),
                            hipFuncAttributeMaxDynamicSharedMemorySize, LDS_BYTES);
  (void)hipFuncSetAttribute(reinterpret_cast<const void*>(&gemm8p<1, 1152, 18>),
                            hipFuncAttributeMaxDynamicSharedMemorySize, LDS_BYTES);

  ln_kernel<<<T_, 256, 0, stream>>>(x, ln_g, ln_b, xn);
  cvt_cat_wqkvg<<<(4 * 147456 + 255) / 256, 256, 0, stream>>>(Wq, Wk, Wv, Wg, Wqkvg);
  cvt_wo_pad<<<(1280 * 1152 + 255) / 256, 256, 0, stream>>>(Wo, Wob);

  dim3 g1(1536 / 256, (T_ * 3) / 256);   // (6, 192) = 1152 blocks, %8==0
  gemm8p<0, 384, 6><<<g1, 512, LDS_BYTES, stream>>>(
      xn, Wqkvg, 1536, QKVG, bq, bk, bv, bg, nullptr, nullptr, nullptr, nullptr);

  attn_kernel<<<(T_ * H_ * 3) / 256, 256, 0, stream>>>(QKVG, Hf);

  dim3 g2(1280 / 256, T_ / 256);         // (5, 64) = 320 blocks, %8==0
  gemm8p<1, 1152, 18><<<g2, 512, LDS_BYTES, stream>>>(
      Hf, Wob, 1152, nullptr, nullptr, nullptr, nullptr, nullptr,
      out, bo, x, g);
}

// Round 13
// 261.982 us; speedup vs baseline: 1.5805x; 1.5805x over previous
//
#include <hip/hip_runtime.h>

#define B_ 4
#define L_ 4096
#define D_ 1152
#define T_ (B_*L_)      // 16384 tokens
#define D3_ 384
#define H_ 16

typedef __attribute__((ext_vector_type(4))) float f32x4;
typedef __attribute__((ext_vector_type(8))) __bf16 bf16x8;
typedef __attribute__((ext_vector_type(8))) unsigned short u16x8;
typedef __attribute__((ext_vector_type(4))) unsigned short u16x4;

__device__ __forceinline__ unsigned short f2bf(float f) {
  unsigned int u = __float_as_uint(f);
  u += 0x7fffu + ((u >> 16) & 1u);
  return (unsigned short)(u >> 16);
}
__device__ __forceinline__ float bf2f(unsigned short h) {
  return __uint_as_float(((unsigned int)h) << 16);
}

__device__ __forceinline__ void gl_lds16(const unsigned short* g, unsigned short* l) {
  __builtin_amdgcn_global_load_lds(
      (const __attribute__((address_space(1))) unsigned int*)g,
      (__attribute__((address_space(3))) unsigned int*)l,
      16, 0, 0);
}

#define SBR __builtin_amdgcn_sched_barrier(0)

// ---------------- LayerNorm: fp32 [16384,1152] -> bf16 ----------------
__global__ __launch_bounds__(256) void ln_kernel(const float* __restrict__ x,
                                                 const float* __restrict__ gamma,
                                                 const float* __restrict__ beta,
                                                 unsigned short* __restrict__ xn) {
  const int row = blockIdx.x;
  const int tid = threadIdx.x;
  const float4* xr = (const float4*)(x + (size_t)row * D_);
  float4 v0 = xr[tid];
  float4 v1 = {0.f, 0.f, 0.f, 0.f};
  const bool has2 = tid < 32;
  if (has2) v1 = xr[256 + tid];
  float s  = v0.x + v0.y + v0.z + v0.w + v1.x + v1.y + v1.z + v1.w;
  float s2 = v0.x*v0.x + v0.y*v0.y + v0.z*v0.z + v0.w*v0.w
           + v1.x*v1.x + v1.y*v1.y + v1.z*v1.z + v1.w*v1.w;
#pragma unroll
  for (int o = 32; o > 0; o >>= 1) { s += __shfl_down(s, o); s2 += __shfl_down(s2, o); }
  __shared__ float red[8];
  int wid = tid >> 6, lane = tid & 63;
  if (lane == 0) { red[wid] = s; red[4 + wid] = s2; }
  __syncthreads();
  float ts  = red[0] + red[1] + red[2] + red[3];
  float ts2 = red[4] + red[5] + red[6] + red[7];
  const float inv = 1.f / (float)D_;
  float mean = ts * inv;
  float var  = ts2 * inv - mean * mean;
  float rstd = rsqrtf(var + 1e-6f);
  const float4* gm = (const float4*)gamma;
  const float4* bt = (const float4*)beta;
  unsigned short* xo = xn + (size_t)row * D_;
  {
    float4 gv = gm[tid], bv = bt[tid];
    u16x4 r;
    r[0] = f2bf((v0.x - mean) * rstd * gv.x + bv.x);
    r[1] = f2bf((v0.y - mean) * rstd * gv.y + bv.y);
    r[2] = f2bf((v0.z - mean) * rstd * gv.z + bv.z);
    r[3] = f2bf((v0.w - mean) * rstd * gv.w + bv.w);
    *(u16x4*)(xo + tid * 4) = r;
  }
  if (has2) {
    float4 gv = gm[256 + tid], bv = bt[256 + tid];
    u16x4 r;
    r[0] = f2bf((v1.x - mean) * rstd * gv.x + bv.x);
    r[1] = f2bf((v1.y - mean) * rstd * gv.y + bv.y);
    r[2] = f2bf((v1.z - mean) * rstd * gv.z + bv.z);
    r[3] = f2bf((v1.w - mean) * rstd * gv.w + bv.w);
    *(u16x4*)(xo + (256 + tid) * 4) = r;
  }
}

// ---------------- Merged weight convert ----------------
__global__ void cvt_all(const float* __restrict__ Wq, const float* __restrict__ Wk,
                        const float* __restrict__ Wv, const float* __restrict__ Wg,
                        const float* __restrict__ Wo,
                        unsigned short* __restrict__ oQ, unsigned short* __restrict__ oO) {
  int i = blockIdx.x * 256 + threadIdx.x;
  const int n1 = 4 * 147456;
  if (i < n1) {
    int p = i / 147456;
    int r = i - p * 147456;
    const float* W = (p == 0) ? Wq : (p == 1) ? Wk : (p == 2) ? Wv : Wg;
    oQ[i] = f2bf(W[r]);
  } else {
    int j = i - n1;
    if (j < 1152 * 1152) oO[j] = f2bf(Wo[j]);
  }
}

// ---------------- gemm1: C[49152,1536] = xn @ Wqkvg^T, minimum-2-phase ----------------
// BM=BN=128, BK=32, 512 thr = 8 waves (2M x 4N), wave-tile 64x32 (4x2 frags).
// dbuf-2 (32KB) -> 4 blocks/CU = 32 waves/CU. ONE barrier per K-step:
//   STAGE(buf^1,t+1); ds_read(buf); lgkmcnt0; MFMA; vmcnt0; barrier.
// Zero-conflict swizzle (R7-verified). nk = 12.

__global__ __launch_bounds__(512) void gemm1_d0(
    const unsigned short* __restrict__ A, const unsigned short* __restrict__ Bt,
    unsigned short* __restrict__ Cb,
    const float* __restrict__ b0, const float* __restrict__ b1,
    const float* __restrict__ b2, const float* __restrict__ b3) {
  const int K = 384, N = 1536;
  __shared__ __align__(16) unsigned short As[2][128 * 32];
  __shared__ __align__(16) unsigned short Bs[2][128 * 32];
  const int tid = threadIdx.x;
  const int nwg = gridDim.x * gridDim.y;
  const int flat = blockIdx.y * gridDim.x + blockIdx.x;
  const int swz = (flat & 7) * (nwg >> 3) + (flat >> 3);
  const int bn = swz % gridDim.x, bm = swz / gridDim.x;

  const int wid = tid >> 6, lane = tid & 63;
  const int wm = wid >> 2, wn = wid & 3;
  const int lrow = lane & 15, kq = lane >> 4;
  const int glr = lane >> 2;
  const int glc = ((lane & 3) ^ ((glr >> 1) & 3)) * 8;
  const int kqs = (kq ^ ((lrow >> 1) & 3)) * 16;

  const unsigned short* Ab = A + (size_t)bm * 128 * K;
  const unsigned short* Bb = Bt + (size_t)bn * 128 * K;

  f32x4 acc[4][2];
#pragma unroll
  for (int m = 0; m < 4; ++m)
#pragma unroll
    for (int n = 0; n < 2; ++n) acc[m][n] = (f32x4){0.f, 0.f, 0.f, 0.f};

  int aoff[4], boff[2];
#pragma unroll
  for (int m = 0; m < 4; ++m) aoff[m] = (wm * 64 + m * 16 + lrow) * 64 + kqs;
#pragma unroll
  for (int n = 0; n < 2; ++n) boff[n] = (wn * 32 + n * 16 + lrow) * 64 + kqs;

#define STAGE1(J, kt)                                                         \
  {                                                                           \
    gl_lds16(Ab + (size_t)(wid * 16 + glr) * K + (kt) * 32 + glc,             \
             &As[J][wid * 512]);                                              \
    gl_lds16(Bb + (size_t)(wid * 16 + glr) * K + (kt) * 32 + glc,             \
             &Bs[J][wid * 512]);                                              \
  }

#define KSTEP1(J, kt, DOSTAGE)                                                \
  {                                                                           \
    if (DOSTAGE) STAGE1((J) ^ 1, (kt) + 1);                                   \
    bf16x8 af[4], bfr[2];                                                     \
    _Pragma("unroll")                                                         \
    for (int m = 0; m < 4; ++m)                                               \
      af[m] = *(const bf16x8*)((const char*)As[J] + aoff[m]);                 \
    _Pragma("unroll")                                                         \
    for (int n = 0; n < 2; ++n)                                               \
      bfr[n] = *(const bf16x8*)((const char*)Bs[J] + boff[n]);                \
    asm volatile("s_waitcnt lgkmcnt(0)" ::: "memory");                        \
    SBR;                                                                      \
    __builtin_amdgcn_s_setprio(1);                                            \
    _Pragma("unroll")                                                         \
    for (int m = 0; m < 4; ++m)                                               \
      _Pragma("unroll")                                                       \
      for (int n = 0; n < 2; ++n)                                             \
        acc[m][n] = __builtin_amdgcn_mfma_f32_16x16x32_bf16(af[m], bfr[n],    \
                                                            acc[m][n], 0,0,0);\
    __builtin_amdgcn_s_setprio(0);                                            \
    asm volatile("s_waitcnt vmcnt(0)" ::: "memory");                          \
    SBR;                                                                      \
    __builtin_amdgcn_s_barrier();                                             \
    SBR;                                                                      \
  }

  STAGE1(0, 0);
  asm volatile("s_waitcnt vmcnt(0)" ::: "memory");
  SBR;
  __builtin_amdgcn_s_barrier();
  SBR;

#pragma unroll 1
  for (int t = 0; t < 12; t += 2) {
    KSTEP1(0, t, true);
    KSTEP1(1, t + 1, (t + 2 < 12));
  }
#undef KSTEP1
#undef STAGE1

  // Epilogue. D layout: col = lane&15, row = (lane>>4)*4 + reg  [m89-verified]
  const int rbase = bm * 128 + wm * 64 + kq * 4;
  const int cbase = bn * 128 + wn * 32 + lrow;
#pragma unroll
  for (int m = 0; m < 4; ++m) {
#pragma unroll
    for (int n = 0; n < 2; ++n) {
      int col = cbase + n * 16;
      int p = (col < 384) ? 0 : (col < 768) ? 1 : (col < 1152) ? 2 : 3;
      const float* bp = (p == 0) ? b0 : (p == 1) ? b1 : (p == 2) ? b2 : b3;
      float bias = bp[col - p * 384];
#pragma unroll
      for (int i = 0; i < 4; ++i) {
        int row = rbase + m * 16 + i;
        Cb[(size_t)row * N + col] = f2bf(acc[m][n][i] + bias);
      }
    }
  }
}

// ---------------- gemm2: out = Hf @ Wo^T + bo + x*g, minimum-2-phase ----------------
// BM=128, BN=96, BK=32, 384 thr = 6 waves (2M x 3N), wave-tile 64x32 (4x2).
// dbuf-2 = 28KB -> 5 blocks/CU = 30 waves/CU. One barrier/K-step (drain-0
// tolerates uneven per-wave stage counts). nk = 36. Grid (12,128)=1536.

__global__ __launch_bounds__(384) void gemm2_d0(
    const unsigned short* __restrict__ A, const unsigned short* __restrict__ Bt,
    float* __restrict__ Cf, const float* __restrict__ bo,
    const float* __restrict__ xres, const float* __restrict__ gs) {
  const int K = 1152, N = 1152, NT = 96;
  __shared__ __align__(16) unsigned short As[2][128 * 32];
  __shared__ __align__(16) unsigned short Bs[2][96 * 32];
  const int tid = threadIdx.x;
  const int nwg = gridDim.x * gridDim.y;
  const int flat = blockIdx.y * gridDim.x + blockIdx.x;
  const int swz = (flat & 7) * (nwg >> 3) + (flat >> 3);
  const int bn = swz % gridDim.x, bm = swz / gridDim.x;

  const int wid = tid >> 6, lane = tid & 63;
  const int wm = wid / 3, wn = wid % 3;
  const int lrow = lane & 15, kq = lane >> 4;
  const int glr = lane >> 2;
  const int glc = ((lane & 3) ^ ((glr >> 1) & 3)) * 8;
  const int kqs = (kq ^ ((lrow >> 1) & 3)) * 16;

  const unsigned short* Ab = A + (size_t)bm * 128 * K;
  const unsigned short* Bb = Bt + (size_t)bn * NT * K;

  f32x4 acc[4][2];
#pragma unroll
  for (int m = 0; m < 4; ++m)
#pragma unroll
    for (int n = 0; n < 2; ++n) acc[m][n] = (f32x4){0.f, 0.f, 0.f, 0.f};

  int aoff[4], boff[2];
#pragma unroll
  for (int m = 0; m < 4; ++m) aoff[m] = (wm * 64 + m * 16 + lrow) * 64 + kqs;
#pragma unroll
  for (int n = 0; n < 2; ++n) boff[n] = (wn * 32 + n * 16 + lrow) * 64 + kqs;

  // 14 stage units of 1KB: u<8 -> A rows u*16; else B rows (u-8)*16.
  // wave w takes units {w, w+6, w+12<14}.
#define STGU(J, kt, u)                                                        \
  {                                                                           \
    if ((u) < 8)                                                              \
      gl_lds16(Ab + (size_t)((u) * 16 + glr) * K + (kt) * 32 + glc,           \
               &As[J][(u) * 512]);                                            \
    else                                                                      \
      gl_lds16(Bb + (size_t)(((u) - 8) * 16 + glr) * K + (kt) * 32 + glc,     \
               &Bs[J][((u) - 8) * 512]);                                      \
  }

#define STAGE2(J, kt)                                                         \
  {                                                                           \
    STGU(J, kt, wid);                                                         \
    STGU(J, kt, wid + 6);                                                     \
    if (wid < 2) STGU(J, kt, wid + 12);                                       \
  }

#define KSTEP2(J, kt, DOSTAGE)                                                \
  {                                                                           \
    if (DOSTAGE) STAGE2((J) ^ 1, (kt) + 1);                                   \
    bf16x8 af[4], bfr[2];                                                     \
    _Pragma("unroll")                                                         \
    for (int m = 0; m < 4; ++m)                                               \
      af[m] = *(const bf16x8*)((const char*)As[J] + aoff[m]);                 \
    _Pragma("unroll")                                                         \
    for (int n = 0; n < 2; ++n)                                               \
      bfr[n] = *(const bf16x8*)((const char*)Bs[J] + boff[n]);                \
    asm volatile("s_waitcnt lgkmcnt(0)" ::: "memory");                        \
    SBR;                                                                      \
    __builtin_amdgcn_s_setprio(1);                                            \
    _Pragma("unroll")                                                         \
    for (int m = 0; m < 4; ++m)                                               \
      _Pragma("unroll")                                                       \
      for (int n = 0; n < 2; ++n)                                             \
        acc[m][n] = __builtin_amdgcn_mfma_f32_16x16x32_bf16(af[m], bfr[n],    \
                                                            acc[m][n], 0,0,0);\
    __builtin_amdgcn_s_setprio(0);                                            \
    asm volatile("s_waitcnt vmcnt(0)" ::: "memory");                          \
    SBR;                                                                      \
    __builtin_amdgcn_s_barrier();                                             \
    SBR;                                                                      \
  }

  STAGE2(0, 0);
  asm volatile("s_waitcnt vmcnt(0)" ::: "memory");
  SBR;
  __builtin_amdgcn_s_barrier();
  SBR;

#pragma unroll 1
  for (int t = 0; t < 36; t += 2) {
    KSTEP2(0, t, true);
    KSTEP2(1, t + 1, (t + 2 < 36));
  }
#undef KSTEP2
#undef STAGE2
#undef STGU

  const int rbase = bm * 128 + wm * 64 + kq * 4;
  const int cbase = bn * NT + wn * 32 + lrow;
  float gv = gs[0];
#pragma unroll
  for (int m = 0; m < 4; ++m) {
#pragma unroll
    for (int n = 0; n < 2; ++n) {
      int col = cbase + n * 16;
      float bias = bo[col];
#pragma unroll
      for (int i = 0; i < 4; ++i) {
        int row = rbase + m * 16 + i;
        size_t idx = (size_t)row * N + col;
        Cf[idx] = acc[m][n][i] + bias + xres[idx] * gv;
      }
    }
  }
}

// ---------------- 3x3 attention + gate ----------------
__global__ __launch_bounds__(256) void attn_kernel(const unsigned short* __restrict__ QKVG,
                                                   unsigned short* __restrict__ Hout) {
  int u = blockIdx.x * 256 + threadIdx.x;
  int h = u & 15;
  int ti = u >> 4;
  int i = ti % 3;
  int t = ti / 3;
  const unsigned short* base = QKVG + (size_t)t * 3 * 1536;
  const int co = h * 24;

  float q[24];
#pragma unroll
  for (int c = 0; c < 3; ++c) {
    u16x8 w = *(const u16x8*)(base + (size_t)i * 1536 + co + c * 8);
#pragma unroll
    for (int e = 0; e < 8; ++e) q[c * 8 + e] = bf2f(w[e]);
  }
  float s[3];
#pragma unroll
  for (int j = 0; j < 3; ++j) {
    float a = 0.f;
#pragma unroll
    for (int c = 0; c < 3; ++c) {
      u16x8 w = *(const u16x8*)(base + (size_t)j * 1536 + 384 + co + c * 8);
#pragma unroll
      for (int e = 0; e < 8; ++e) a += q[c * 8 + e] * bf2f(w[e]);
    }
    s[j] = a * 0.11785113019775793f;
  }
  float mx = fmaxf(s[0], fmaxf(s[1], s[2]));
  float e0 = __expf(s[0] - mx), e1 = __expf(s[1] - mx), e2 = __expf(s[2] - mx);
  float inv = 1.f / (e0 + e1 + e2);
  float p0 = e0 * inv, p1 = e1 * inv, p2 = e2 * inv;

  float o[24];
#pragma unroll
  for (int d = 0; d < 24; ++d) o[d] = 0.f;
  float pj[3] = {p0, p1, p2};
#pragma unroll
  for (int j = 0; j < 3; ++j) {
#pragma unroll
    for (int c = 0; c < 3; ++c) {
      u16x8 w = *(const u16x8*)(base + (size_t)j * 1536 + 768 + co + c * 8);
#pragma unroll
      for (int e = 0; e < 8; ++e) o[c * 8 + e] += pj[j] * bf2f(w[e]);
    }
  }
  unsigned short* op = Hout + (size_t)t * 1152 + (size_t)i * 384 + co;
#pragma unroll
  for (int c = 0; c < 3; ++c) {
    u16x8 w = *(const u16x8*)(base + (size_t)i * 1536 + 1152 + co + c * 8);
    u16x8 r;
#pragma unroll
    for (int e = 0; e < 8; ++e) {
      float gvv = bf2f(w[e]);
      float sg = 1.f / (1.f + __expf(-gvv));
      r[e] = f2bf(o[c * 8 + e] * sg);
    }
    *(u16x8*)(op + c * 8) = r;
  }
}

extern "C" void kernel_launch(void* const* d_in, const int* in_sizes, int n_in,
                              void* d_out, int out_size, void* d_ws, size_t ws_size,
                              hipStream_t stream) {
  const float* x    = (const float*)d_in[0];
  const float* ln_g = (const float*)d_in[1];
  const float* ln_b = (const float*)d_in[2];
  const float* Wq   = (const float*)d_in[3];
  const float* bq   = (const float*)d_in[4];
  const float* Wk   = (const float*)d_in[5];
  const float* bk   = (const float*)d_in[6];
  const float* Wv   = (const float*)d_in[7];
  const float* bv   = (const float*)d_in[8];
  const float* Wg   = (const float*)d_in[9];
  const float* bg   = (const float*)d_in[10];
  const float* Wo   = (const float*)d_in[11];
  const float* bo   = (const float*)d_in[12];
  const float* g    = (const float*)d_in[13];
  float* out = (float*)d_out;

  char* ws = (char*)d_ws;
  size_t off = 0;
  unsigned short* xn    = (unsigned short*)(ws + off); off += (size_t)T_ * D_ * 2;
  unsigned short* Wqkvg = (unsigned short*)(ws + off); off += (size_t)1536 * 384 * 2;
  unsigned short* Wob   = (unsigned short*)(ws + off); off += (size_t)1152 * 1152 * 2;
  unsigned short* QKVG  = (unsigned short*)(ws + off); off += (size_t)T_ * 3 * 1536 * 2;
  unsigned short* Hf    = (unsigned short*)(ws + off); off += (size_t)T_ * D_ * 2;

  ln_kernel<<<T_, 256, 0, stream>>>(x, ln_g, ln_b, xn);
  const int ncvt = 4 * 147456 + 1152 * 1152;
  cvt_all<<<(ncvt + 255) / 256, 256, 0, stream>>>(Wq, Wk, Wv, Wg, Wo, Wqkvg, Wob);

  dim3 g1(1536 / 128, (T_ * 3) / 128);   // (12, 384) nwg=4608
  gemm1_d0<<<g1, 512, 0, stream>>>(xn, Wqkvg, QKVG, bq, bk, bv, bg);

  attn_kernel<<<(T_ * H_ * 3) / 256, 256, 0, stream>>>(QKVG, Hf);

  dim3 g2(1152 / 96, T_ / 128);          // (12, 128) nwg=1536
  gemm2_d0<<<g2, 384, 0, stream>>>(Hf, Wob, out, bo, x, g);
}

// Round 14
// 202.507 us; speedup vs baseline: 2.0447x; 1.2937x over previous
//
#include <hip/hip_runtime.h>

#define B_ 4
#define L_ 4096
#define D_ 1152
#define T_ (B_*L_)      // 16384 tokens
#define D3_ 384
#define H_ 16

typedef __attribute__((ext_vector_type(4))) float f32x4;
typedef __attribute__((ext_vector_type(8))) __bf16 bf16x8;
typedef __attribute__((ext_vector_type(8))) unsigned short u16x8;
typedef __attribute__((ext_vector_type(4))) unsigned short u16x4;

__device__ __forceinline__ unsigned short f2bf(float f) {
  unsigned int u = __float_as_uint(f);
  u += 0x7fffu + ((u >> 16) & 1u);
  return (unsigned short)(u >> 16);
}
__device__ __forceinline__ float bf2f(unsigned short h) {
  return __uint_as_float(((unsigned int)h) << 16);
}

__device__ __forceinline__ void gl_lds16(const unsigned short* g, unsigned short* l) {
  __builtin_amdgcn_global_load_lds(
      (const __attribute__((address_space(1))) unsigned int*)g,
      (__attribute__((address_space(3))) unsigned int*)l,
      16, 0, 0);
}

#define SBR __builtin_amdgcn_sched_barrier(0)

// ---------------- LayerNorm: fp32 [16384,1152] -> bf16 ----------------
__global__ __launch_bounds__(256) void ln_kernel(const float* __restrict__ x,
                                                 const float* __restrict__ gamma,
                                                 const float* __restrict__ beta,
                                                 unsigned short* __restrict__ xn) {
  const int row = blockIdx.x;
  const int tid = threadIdx.x;
  const float4* xr = (const float4*)(x + (size_t)row * D_);
  float4 v0 = xr[tid];
  float4 v1 = {0.f, 0.f, 0.f, 0.f};
  const bool has2 = tid < 32;
  if (has2) v1 = xr[256 + tid];
  float s  = v0.x + v0.y + v0.z + v0.w + v1.x + v1.y + v1.z + v1.w;
  float s2 = v0.x*v0.x + v0.y*v0.y + v0.z*v0.z + v0.w*v0.w
           + v1.x*v1.x + v1.y*v1.y + v1.z*v1.z + v1.w*v1.w;
#pragma unroll
  for (int o = 32; o > 0; o >>= 1) { s += __shfl_down(s, o); s2 += __shfl_down(s2, o); }
  __shared__ float red[8];
  int wid = tid >> 6, lane = tid & 63;
  if (lane == 0) { red[wid] = s; red[4 + wid] = s2; }
  __syncthreads();
  float ts  = red[0] + red[1] + red[2] + red[3];
  float ts2 = red[4] + red[5] + red[6] + red[7];
  const float inv = 1.f / (float)D_;
  float mean = ts * inv;
  float var  = ts2 * inv - mean * mean;
  float rstd = rsqrtf(var + 1e-6f);
  const float4* gm = (const float4*)gamma;
  const float4* bt = (const float4*)beta;
  unsigned short* xo = xn + (size_t)row * D_;
  {
    float4 gv = gm[tid], bv = bt[tid];
    u16x4 r;
    r[0] = f2bf((v0.x - mean) * rstd * gv.x + bv.x);
    r[1] = f2bf((v0.y - mean) * rstd * gv.y + bv.y);
    r[2] = f2bf((v0.z - mean) * rstd * gv.z + bv.z);
    r[3] = f2bf((v0.w - mean) * rstd * gv.w + bv.w);
    *(u16x4*)(xo + tid * 4) = r;
  }
  if (has2) {
    float4 gv = gm[256 + tid], bv = bt[256 + tid];
    u16x4 r;
    r[0] = f2bf((v1.x - mean) * rstd * gv.x + bv.x);
    r[1] = f2bf((v1.y - mean) * rstd * gv.y + bv.y);
    r[2] = f2bf((v1.z - mean) * rstd * gv.z + bv.z);
    r[3] = f2bf((v1.w - mean) * rstd * gv.w + bv.w);
    *(u16x4*)(xo + (256 + tid) * 4) = r;
  }
}

// ---------------- Merged weight convert, head-permuted QKVG ----------------
// Wperm row r = h*96 + p*24 + d  <-  W_p[(h*24+d), :]   (p: 0=q,1=k,2=v,3=g)
// bperm[r] = b_p[h*24+d]
__global__ void cvt_all(const float* __restrict__ Wq, const float* __restrict__ Wk,
                        const float* __restrict__ Wv, const float* __restrict__ Wg,
                        const float* __restrict__ Wo,
                        const float* __restrict__ bq, const float* __restrict__ bk,
                        const float* __restrict__ bv, const float* __restrict__ bg,
                        unsigned short* __restrict__ oQ, unsigned short* __restrict__ oO,
                        float* __restrict__ ob) {
  int i = blockIdx.x * 256 + threadIdx.x;
  const int n1 = 1536 * 384;
  const int n2 = 1152 * 1152;
  if (i < n1) {
    int r = i / 384, c = i - r * 384;
    int h = r / 96, pp = (r / 24) & 3, d = r % 24;
    const float* W = (pp == 0) ? Wq : (pp == 1) ? Wk : (pp == 2) ? Wv : Wg;
    oQ[i] = f2bf(W[(h * 24 + d) * 384 + c]);
  } else if (i < n1 + n2) {
    int j = i - n1;
    oO[j] = f2bf(Wo[j]);
  } else if (i < n1 + n2 + 1536) {
    int r = i - n1 - n2;
    int h = r / 96, pp = (r / 24) & 3, d = r % 24;
    const float* bp = (pp == 0) ? bq : (pp == 1) ? bk : (pp == 2) ? bv : bg;
    ob[r] = bp[h * 24 + d];
  }
}

// ---------------- gemm1 fused with 3x3 attention + gate ----------------
// C-tile = 192 rows (64 tokens x 3 groups) x 96 cols (one head: q|k|v|g strips).
// BK=32, 512 thr = 8 waves (4M x 2N), wave-tile 48x48 (3x3 frags, acc=36 VGPR).
// dbuf-2 LDS = 36KB -> 4 blocks/CU = 32 waves/CU. One barrier per K-step
// (R13-verified). Zero-conflict swizzle. nk=12. Epilogue: tile -> LDS (reuse
// staging), 192 threads do per-(token,group) 3x3 softmax + sigmoid gate,
// write Hf[t, i*384 + h*24 + d] directly. QKVG never materialized.

__global__ __launch_bounds__(512) void gemm1_fused(
    const unsigned short* __restrict__ A, const unsigned short* __restrict__ Bp,
    unsigned short* __restrict__ Hout, const float* __restrict__ bperm) {
  const int K = 384;
  __shared__ __align__(16) unsigned short smem[2 * 6144 + 2 * 3072];  // 36 KB
  unsigned short* AsB = smem;           // [2][192*32]
  unsigned short* BsB = smem + 12288;   // [2][96*32]
  const int tid = threadIdx.x;
  const int nwg = gridDim.x * gridDim.y;
  const int flat = blockIdx.y * gridDim.x + blockIdx.x;
  const int swz = (flat & 7) * (nwg >> 3) + (flat >> 3);
  const int bn = swz % gridDim.x, bm = swz / gridDim.x;   // bn = head

  const int wid = tid >> 6, lane = tid & 63;
  const int wm = wid >> 1, wn = wid & 1;       // 4M x 2N, wave-tile 48x48
  const int lrow = lane & 15, kq = lane >> 4;
  const int glr = lane >> 2;
  const int glc = ((lane & 3) ^ ((glr >> 1) & 3)) * 8;
  const int kqs = (kq ^ ((lrow >> 1) & 3)) * 16;

  const unsigned short* Ab = A + (size_t)bm * 192 * K;
  const unsigned short* Bb = Bp + (size_t)bn * 96 * K;

  f32x4 acc[3][3];
#pragma unroll
  for (int m = 0; m < 3; ++m)
#pragma unroll
    for (int n = 0; n < 3; ++n) acc[m][n] = (f32x4){0.f, 0.f, 0.f, 0.f};

  int aoff[3], boff[3];
#pragma unroll
  for (int m = 0; m < 3; ++m) aoff[m] = (wm * 48 + m * 16 + lrow) * 64 + kqs;
#pragma unroll
  for (int n = 0; n < 3; ++n) boff[n] = (wn * 48 + n * 16 + lrow) * 64 + kqs;

  // 18 stage units of 1KB (A: 12, B: 6). wave w: units {w, w+8, w+16 if w<2}.
#define STAGE1(J, kt)                                                         \
  {                                                                           \
    gl_lds16(Ab + (size_t)(wid * 16 + glr) * K + (kt) * 32 + glc,             \
             AsB + (J) * 6144 + wid * 512);                                   \
    if (wid < 4)                                                              \
      gl_lds16(Ab + (size_t)((wid + 8) * 16 + glr) * K + (kt) * 32 + glc,     \
               AsB + (J) * 6144 + (wid + 8) * 512);                           \
    else                                                                      \
      gl_lds16(Bb + (size_t)((wid - 4) * 16 + glr) * K + (kt) * 32 + glc,     \
               BsB + (J) * 3072 + (wid - 4) * 512);                           \
    if (wid < 2)                                                              \
      gl_lds16(Bb + (size_t)((wid + 4) * 16 + glr) * K + (kt) * 32 + glc,     \
               BsB + (J) * 3072 + (wid + 4) * 512);                           \
  }

#define KSTEP1(J, kt, DOSTAGE)                                                \
  {                                                                           \
    if (DOSTAGE) STAGE1((J) ^ 1, (kt) + 1);                                   \
    bf16x8 af[3], bfr[3];                                                     \
    _Pragma("unroll")                                                         \
    for (int m = 0; m < 3; ++m)                                               \
      af[m] = *(const bf16x8*)((const char*)(AsB + (J) * 6144) + aoff[m]);    \
    _Pragma("unroll")                                                         \
    for (int n = 0; n < 3; ++n)                                               \
      bfr[n] = *(const bf16x8*)((const char*)(BsB + (J) * 3072) + boff[n]);   \
    asm volatile("s_waitcnt lgkmcnt(0)" ::: "memory");                        \
    SBR;                                                                      \
    __builtin_amdgcn_s_setprio(1);                                            \
    _Pragma("unroll")                                                         \
    for (int m = 0; m < 3; ++m)                                               \
      _Pragma("unroll")                                                       \
      for (int n = 0; n < 3; ++n)                                             \
        acc[m][n] = __builtin_amdgcn_mfma_f32_16x16x32_bf16(af[m], bfr[n],    \
                                                            acc[m][n], 0,0,0);\
    __builtin_amdgcn_s_setprio(0);                                            \
    asm volatile("s_waitcnt vmcnt(0)" ::: "memory");                          \
    SBR;                                                                      \
    __builtin_amdgcn_s_barrier();                                             \
    SBR;                                                                      \
  }

  STAGE1(0, 0);
  asm volatile("s_waitcnt vmcnt(0)" ::: "memory");
  SBR;
  __builtin_amdgcn_s_barrier();
  SBR;

#pragma unroll 1
  for (int t = 0; t < 12; t += 2) {
    KSTEP1(0, t, true);
    KSTEP1(1, t + 1, (t + 2 < 12));
  }
#undef KSTEP1
#undef STAGE1

  // ---- epilogue part 1: acc (+bias) -> smem[192][96] bf16 ----
  // (all LDS reads of the loop completed before the final barrier)
#pragma unroll
  for (int m = 0; m < 3; ++m) {
#pragma unroll
    for (int n = 0; n < 3; ++n) {
      const int col = wn * 48 + n * 16 + lrow;
      const float bb = bperm[bn * 96 + col];
#pragma unroll
      for (int i = 0; i < 4; ++i) {
        const int row = wm * 48 + m * 16 + kq * 4 + i;
        smem[row * 96 + col] = f2bf(acc[m][n][i] + bb);
      }
    }
  }
  __syncthreads();

  // ---- epilogue part 2: per-(token,group) 3x3 attention + gate ----
  if (tid < 192) {
    const int tl = tid / 3;            // local token 0..63
    const int gi = tid - tl * 3;       // group i
    const unsigned short* rowq = smem + tid * 96;
    float q[24], o[24];
#pragma unroll
    for (int c = 0; c < 3; ++c) {
      u16x8 w = *(const u16x8*)(rowq + c * 8);
#pragma unroll
      for (int e = 0; e < 8; ++e) q[c * 8 + e] = bf2f(w[e]);
    }
    float s[3];
#pragma unroll
    for (int j = 0; j < 3; ++j) {
      const unsigned short* rk = smem + (tl * 3 + j) * 96 + 24;
      float a = 0.f;
#pragma unroll
      for (int c = 0; c < 3; ++c) {
        u16x8 w = *(const u16x8*)(rk + c * 8);
#pragma unroll
        for (int e = 0; e < 8; ++e) a += q[c * 8 + e] * bf2f(w[e]);
      }
      s[j] = a * 0.11785113019775793f;   // 1/sqrt(72)
    }
    float mx = fmaxf(s[0], fmaxf(s[1], s[2]));
    float e0 = __expf(s[0] - mx), e1 = __expf(s[1] - mx), e2 = __expf(s[2] - mx);
    float inv = 1.f / (e0 + e1 + e2);
    float pj[3] = {e0 * inv, e1 * inv, e2 * inv};
#pragma unroll
    for (int d = 0; d < 24; ++d) o[d] = 0.f;
#pragma unroll
    for (int j = 0; j < 3; ++j) {
      const unsigned short* rv = smem + (tl * 3 + j) * 96 + 48;
#pragma unroll
      for (int c = 0; c < 3; ++c) {
        u16x8 w = *(const u16x8*)(rv + c * 8);
#pragma unroll
        for (int e = 0; e < 8; ++e) o[c * 8 + e] += pj[j] * bf2f(w[e]);
      }
    }
    const int t = bm * 64 + tl;
    unsigned short* op = Hout + (size_t)t * 1152 + gi * 384 + bn * 24;
#pragma unroll
    for (int c = 0; c < 3; ++c) {
      u16x8 w = *(const u16x8*)(rowq + 72 + c * 8);
      u16x8 r;
#pragma unroll
      for (int e = 0; e < 8; ++e) {
        float gvv = bf2f(w[e]);
        float sg = 1.f / (1.f + __expf(-gvv));
        r[e] = f2bf(o[c * 8 + e] * sg);
      }
      *(u16x8*)(op + c * 8) = r;
    }
  }
}

// ---------------- gemm2: out = Hf @ Wo^T + bo + x*g  (R13, unchanged) ----------------
__global__ __launch_bounds__(384) void gemm2_d0(
    const unsigned short* __restrict__ A, const unsigned short* __restrict__ Bt,
    float* __restrict__ Cf, const float* __restrict__ bo,
    const float* __restrict__ xres, const float* __restrict__ gs) {
  const int K = 1152, N = 1152, NT = 96;
  __shared__ __align__(16) unsigned short As[2][128 * 32];
  __shared__ __align__(16) unsigned short Bs[2][96 * 32];
  const int tid = threadIdx.x;
  const int nwg = gridDim.x * gridDim.y;
  const int flat = blockIdx.y * gridDim.x + blockIdx.x;
  const int swz = (flat & 7) * (nwg >> 3) + (flat >> 3);
  const int bn = swz % gridDim.x, bm = swz / gridDim.x;

  const int wid = tid >> 6, lane = tid & 63;
  const int wm = wid / 3, wn = wid % 3;
  const int lrow = lane & 15, kq = lane >> 4;
  const int glr = lane >> 2;
  const int glc = ((lane & 3) ^ ((glr >> 1) & 3)) * 8;
  const int kqs = (kq ^ ((lrow >> 1) & 3)) * 16;

  const unsigned short* Ab = A + (size_t)bm * 128 * K;
  const unsigned short* Bb = Bt + (size_t)bn * NT * K;

  f32x4 acc[4][2];
#pragma unroll
  for (int m = 0; m < 4; ++m)
#pragma unroll
    for (int n = 0; n < 2; ++n) acc[m][n] = (f32x4){0.f, 0.f, 0.f, 0.f};

  int aoff[4], boff[2];
#pragma unroll
  for (int m = 0; m < 4; ++m) aoff[m] = (wm * 64 + m * 16 + lrow) * 64 + kqs;
#pragma unroll
  for (int n = 0; n < 2; ++n) boff[n] = (wn * 32 + n * 16 + lrow) * 64 + kqs;

#define STGU(J, kt, u)                                                        \
  {                                                                           \
    if ((u) < 8)                                                              \
      gl_lds16(Ab + (size_t)((u) * 16 + glr) * K + (kt) * 32 + glc,           \
               &As[J][(u) * 512]);                                            \
    else                                                                      \
      gl_lds16(Bb + (size_t)(((u) - 8) * 16 + glr) * K + (kt) * 32 + glc,     \
               &Bs[J][((u) - 8) * 512]);                                      \
  }

#define STAGE2(J, kt)                                                         \
  {                                                                           \
    STGU(J, kt, wid);                                                         \
    STGU(J, kt, wid + 6);                                                     \
    if (wid < 2) STGU(J, kt, wid + 12);                                       \
  }

#define KSTEP2(J, kt, DOSTAGE)                                                \
  {                                                                           \
    if (DOSTAGE) STAGE2((J) ^ 1, (kt) + 1);                                   \
    bf16x8 af[4], bfr[2];                                                     \
    _Pragma("unroll")                                                         \
    for (int m = 0; m < 4; ++m)                                               \
      af[m] = *(const bf16x8*)((const char*)As[J] + aoff[m]);                 \
    _Pragma("unroll")                                                         \
    for (int n = 0; n < 2; ++n)                                               \
      bfr[n] = *(const bf16x8*)((const char*)Bs[J] + boff[n]);                \
    asm volatile("s_waitcnt lgkmcnt(0)" ::: "memory");                        \
    SBR;                                                                      \
    __builtin_amdgcn_s_setprio(1);                                            \
    _Pragma("unroll")                                                         \
    for (int m = 0; m < 4; ++m)                                               \
      _Pragma("unroll")                                                       \
      for (int n = 0; n < 2; ++n)                                             \
        acc[m][n] = __builtin_amdgcn_mfma_f32_16x16x32_bf16(af[m], bfr[n],    \
                                                            acc[m][n], 0,0,0);\
    __builtin_amdgcn_s_setprio(0);                                            \
    asm volatile("s_waitcnt vmcnt(0)" ::: "memory");                          \
    SBR;                                                                      \
    __builtin_amdgcn_s_barrier();                                             \
    SBR;                                                                      \
  }

  STAGE2(0, 0);
  asm volatile("s_waitcnt vmcnt(0)" ::: "memory");
  SBR;
  __builtin_amdgcn_s_barrier();
  SBR;

#pragma unroll 1
  for (int t = 0; t < 36; t += 2) {
    KSTEP2(0, t, true);
    KSTEP2(1, t + 1, (t + 2 < 36));
  }
#undef KSTEP2
#undef STAGE2
#undef STGU

  const int rbase = bm * 128 + wm * 64 + kq * 4;
  const int cbase = bn * NT + wn * 32 + lrow;
  float gv = gs[0];
#pragma unroll
  for (int m = 0; m < 4; ++m) {
#pragma unroll
    for (int n = 0; n < 2; ++n) {
      int col = cbase + n * 16;
      float bias = bo[col];
#pragma unroll
      for (int i = 0; i < 4; ++i) {
        int row = rbase + m * 16 + i;
        size_t idx = (size_t)row * N + col;
        Cf[idx] = acc[m][n][i] + bias + xres[idx] * gv;
      }
    }
  }
}

extern "C" void kernel_launch(void* const* d_in, const int* in_sizes, int n_in,
                              void* d_out, int out_size, void* d_ws, size_t ws_size,
                              hipStream_t stream) {
  const float* x    = (const float*)d_in[0];
  const float* ln_g = (const float*)d_in[1];
  const float* ln_b = (const float*)d_in[2];
  const float* Wq   = (const float*)d_in[3];
  const float* bq   = (const float*)d_in[4];
  const float* Wk   = (const float*)d_in[5];
  const float* bk   = (const float*)d_in[6];
  const float* Wv   = (const float*)d_in[7];
  const float* bv   = (const float*)d_in[8];
  const float* Wg   = (const float*)d_in[9];
  const float* bg   = (const float*)d_in[10];
  const float* Wo   = (const float*)d_in[11];
  const float* bo   = (const float*)d_in[12];
  const float* g    = (const float*)d_in[13];
  float* out = (float*)d_out;

  char* ws = (char*)d_ws;
  size_t off = 0;
  unsigned short* xn    = (unsigned short*)(ws + off); off += (size_t)T_ * D_ * 2;
  unsigned short* Wqkvg = (unsigned short*)(ws + off); off += (size_t)1536 * 384 * 2;
  unsigned short* Wob   = (unsigned short*)(ws + off); off += (size_t)1152 * 1152 * 2;
  float*          bperm = (float*)(ws + off);          off += 1536 * 4;
  unsigned short* Hf    = (unsigned short*)(ws + off); off += (size_t)T_ * D_ * 2;

  ln_kernel<<<T_, 256, 0, stream>>>(x, ln_g, ln_b, xn);
  const int ncvt = 1536 * 384 + 1152 * 1152 + 1536;
  cvt_all<<<(ncvt + 255) / 256, 256, 0, stream>>>(Wq, Wk, Wv, Wg, Wo,
                                                  bq, bk, bv, bg,
                                                  Wqkvg, Wob, bperm);

  dim3 g1(16, (T_ * 3) / 192);   // (16 heads, 256 M-blocks) nwg=4096
  gemm1_fused<<<g1, 512, 0, stream>>>(xn, Wqkvg, Hf, bperm);

  dim3 g2(1152 / 96, T_ / 128);  // (12, 128) nwg=1536
  gemm2_d0<<<g2, 384, 0, stream>>>(Hf, Wob, out, bo, x, g);
}